// Round 10
// baseline (110.238 us; speedup 1.0000x reference)
//
#include <hip/hip_runtime.h>
#include <hip/hip_bf16.h>

// HardAttention = GEMM out=tanh([ctx|outp]@W^T+b) (M=16384,K=1024,N=512, bf16 MFMA)
//               + attn = constant one-hot [4,4096,4096] (256 MiB write stream).
// R7/R9 (74.4us): barrier-free wave-autonomous 64x64 tiles, per-wave LDS staging, native cvt.
// R10 theory: only 8 waves/CU resident (grid 512 blocks) -> ~2.5KB in flight per CU, MLP-
// starved (Little's law needs ~20KB). Shrink wave tile to 64x32 -> 4096 waves = 1024 blocks
// -> 3-4 blocks/CU (12-16 waves/CU). acc halves to 32 VGPR; W staged in 80B-padded LDS rows.

typedef __attribute__((ext_vector_type(8))) short bf16x8;   // 8 bf16 = 4 VGPRs
typedef __attribute__((ext_vector_type(4))) float f32x4;

#define B_N 4
#define L_N 4096
#define S_N 4096
#define D_N 512
#define M_N (B_N * L_N)   // 16384
#define K_N (2 * D_N)     // 1024

#define NTHREADS 256      // 4 waves/block
#define NBLOCKS 1024      // 4096 waves = 256 mtiles(64r) x 16 ntiles(32c)
#define NSTEPS 32         // K / 32

#define LDSW 6656         // per-wave: A 4096 + W 2560

static __device__ __forceinline__ short f2bf(float f) {
  return __builtin_bit_cast(short, __float2bfloat16(f));   // RNE; fuses to v_cvt_pk_bf16_f32
}

static __device__ __forceinline__ bf16x8 pack8(f32x4 a, f32x4 b) {
  bf16x8 r;
  r[0] = f2bf(a.x); r[1] = f2bf(a.y); r[2] = f2bf(a.z); r[3] = f2bf(a.w);
  r[4] = f2bf(b.x); r[5] = f2bf(b.y); r[6] = f2bf(b.z); r[7] = f2bf(b.w);
  return r;
}

__global__ __launch_bounds__(NTHREADS, 3)
void gemm_fill(const float* __restrict__ outp, const float* __restrict__ ctx,
               const float* __restrict__ Wm, const float* __restrict__ bias,
               float* __restrict__ dout)
{
  __shared__ char lds[4][LDSW];

  const int tid  = threadIdx.x;
  const int lane = tid & 63;
  const int wid  = tid >> 6;
  // XCD-chunked bijective swizzle (1024%8==0): XCD x gets logical blocks x*128..x*128+127
  // -> each mtile's 4 blocks (16 waves sharing an A panel) stay in one XCD's L2.
  const int sb = (blockIdx.x & 7) * 128 + (blockIdx.x >> 3);
  const int gwave = sb * 4 + wid;
  const int mtile = gwave >> 4;       // 256 tiles of 64 rows
  const int ntile = gwave & 15;       // 16 tiles of 32 cols
  const int m0 = mtile * 64;
  const int n0 = ntile * 32;

  char* As = lds[wid];                // 64 rows x 64B (32 bf16), XOR-swizzled (R7-verified)
  char* Ws = lds[wid] + 4096;         // 32 rows x 80B (64B data + 16B pad)

  // ---- A staging map (identical to R9): lane -> row lrq (16/q), chunk ch (8 floats)
  const int lrq = lane >> 2;          // 0..15
  const int ch  = lane & 3;           // 0..3
  const int wrA = lrq * 64 + ((ch << 4) ^ (((lrq >> 1) & 3) << 4));          // + q*1024
  const int rdA = (lane & 15) * 64 +
                  ((((lane >> 4) << 4)) ^ ((((lane & 15) >> 1) & 3) << 4));  // + i*1024

  // ---- W staging map: lane -> row wrow (0..31), half wh (16 floats)
  const int wrow = lane & 31;
  const int wh   = lane >> 5;
  const int wrW  = wrow * 80 + wh * 32;                  // write 32B (2 x b128)
  const int rdW  = (lane & 15) * 80 + ((lane >> 4) << 4); // + j*16*80; 2-way = free

  // global staging bases (per-lane)
  const float* aC = ctx  + (size_t)(m0 + lrq) * D_N + ch * 8;    // k-steps 0..15
  const float* aO = outp + (size_t)(m0 + lrq) * D_N + ch * 8;    // k-steps 16..31
  const float* wB = Wm   + (size_t)(n0 + wrow) * K_N + wh * 16;  // full k

  // fill: this wave covers f32x4 indices [gwave*4096, (gwave+1)*4096)
  f32x4* attn4 = (f32x4*)(dout + (size_t)M_N * D_N) + (size_t)gwave * 4096;

  f32x4 acc[4][2] = {};               // 4 row-frags x 2 col-frags = 32 VGPR
  f32x4 sa[8], sw[4];

  // ---- prologue: issue loads for step 0 ----
#pragma unroll
  for (int q = 0; q < 4; ++q) {
    sa[2*q]   = *(const f32x4*)(aC + q * (16 * D_N));
    sa[2*q+1] = *(const f32x4*)(aC + q * (16 * D_N) + 4);
  }
#pragma unroll
  for (int p = 0; p < 4; ++p) sw[p] = *(const f32x4*)(wB + p * 4);

#pragma unroll 1
  for (int t = 0; t < NSTEPS; ++t) {
    // ---- pack + ds_write staged step t (waits loads via counted vmcnt; fill stores fly) ----
#pragma unroll
    for (int q = 0; q < 4; ++q)
      *(bf16x8*)(As + q * 1024 + wrA) = pack8(sa[2*q], sa[2*q+1]);
    *(bf16x8*)(Ws + wrW)      = pack8(sw[0], sw[1]);
    *(bf16x8*)(Ws + wrW + 16) = pack8(sw[2], sw[3]);

    // ---- issue step t+1 loads (staging regs free again) ----
    if (t + 1 < NSTEPS) {
      const int tn = t + 1;
      const float* ab = (tn < 16 ? aC : aO) + (tn & 15) * 32;
      const float* wb = wB + tn * 32;
#pragma unroll
      for (int q = 0; q < 4; ++q) {
        sa[2*q]   = *(const f32x4*)(ab + q * (16 * D_N));
        sa[2*q+1] = *(const f32x4*)(ab + q * (16 * D_N) + 4);
      }
#pragma unroll
      for (int p = 0; p < 4; ++p) sw[p] = *(const f32x4*)(wb + p * 4);
    }

    // ---- fill slice for step t: 2 NT float4 stores/lane, never force-drained ----
#pragma unroll
    for (int s = 0; s < 2; ++s) {
      const int li = t * 128 + (s << 6) + lane;        // local f32x4 idx
      const int gi = (gwave << 12) + li;
      const int col4 = (gi & 1023) << 2;
      const int l    = (gi >> 10) & 4095;
      f32x4 v;
      v.x = (col4     == l) ? 1.0f : 0.0f;
      v.y = (col4 + 1 == l) ? 1.0f : 0.0f;
      v.z = (col4 + 2 == l) ? 1.0f : 0.0f;
      v.w = (col4 + 3 == l) ? 1.0f : 0.0f;
      __builtin_nontemporal_store(v, attn4 + li);
    }

    // ---- fragments (lgkmcnt-counted, same wave) + 8 MFMA ----
    bf16x8 af[4], wf[2];
#pragma unroll
    for (int i = 0; i < 4; ++i) af[i] = *(const bf16x8*)(As + i * 1024 + rdA);
#pragma unroll
    for (int j = 0; j < 2; ++j) wf[j] = *(const bf16x8*)(Ws + j * 1280 + rdW);
#pragma unroll
    for (int i = 0; i < 4; ++i)
#pragma unroll
      for (int j = 0; j < 2; ++j)
        acc[i][j] = __builtin_amdgcn_mfma_f32_16x16x32_bf16(af[i], wf[j], acc[i][j], 0, 0, 0);
  }

  // ---- epilogue: C/D layout col=lane&15, row=(lane>>4)*4+reg (verified R1/m89/m91) ----
  const int r0  = m0 + ((lane >> 4) << 2);
  const int c0g = n0 + (lane & 15);
  float bv[2];
#pragma unroll
  for (int j = 0; j < 2; ++j) bv[j] = bias[c0g + j * 16];
#pragma unroll
  for (int i = 0; i < 4; ++i)
#pragma unroll
    for (int j = 0; j < 2; ++j)
#pragma unroll
      for (int r = 0; r < 4; ++r) {
        const int m = r0 + i * 16 + r;
        const int n = c0g + j * 16;
        dout[(size_t)m * D_N + n] = tanhf(acc[i][j][r] + bv[j]);
      }
}

extern "C" void kernel_launch(void* const* d_in, const int* in_sizes, int n_in,
                              void* d_out, int out_size, void* d_ws, size_t ws_size,
                              hipStream_t stream) {
  const float* outp = (const float*)d_in[0];
  const float* ctx  = (const float*)d_in[1];
  const float* Wm   = (const float*)d_in[2];
  const float* bias = (const float*)d_in[3];
  float* dout = (float*)d_out;
  hipLaunchKernelGGL(gemm_fill, dim3(NBLOCKS), dim3(NTHREADS), 0, stream,
                     outp, ctx, Wm, bias, dout);
}